// Round 3
// baseline (314.863 us; speedup 1.0000x reference)
//
#include <hip/hip_runtime.h>
#include <hip/hip_bf16.h>
#include <math.h>

// Problem constants (B,D,N from reference)
#define MDIM 4096   // batch rows
#define KDIM 2048   // feature dim D
#define NDIM 4096   // output dim N
#define DT   0.01f
#define TWO_PI_F 6.283185307179586f
#define CH 64       // scan chunks
#define CL 64       // steps per chunk  (CH*CL == MDIM)
#define TILES (KDIM / 64)   // 32 K-tiles of BK=64

typedef __attribute__((ext_vector_type(8))) short bf16x8;
typedef __attribute__((ext_vector_type(4))) float f32x4;

__device__ __forceinline__ unsigned short f2bf(float f) {
  unsigned int u = __float_as_uint(f);
  u += 0x7FFFu + ((u >> 16) & 1u);           // round-to-nearest-even
  return (unsigned short)(u >> 16);
}
__device__ __forceinline__ float bf2f(unsigned short u) {
  return __uint_as_float(((unsigned int)u) << 16);
}

// -------- fused cast fp32 -> bf16 for x and W (both 8M floats) --------
__global__ void cast2_bf16_kernel(const float* __restrict__ s0,
                                  unsigned short* __restrict__ d0,
                                  const float* __restrict__ s1,
                                  unsigned short* __restrict__ d1,
                                  int n4each) {
  int i = blockIdx.x * blockDim.x + threadIdx.x;
  const float4* sp;
  ushort4* dp;
  int j;
  if (i < n4each) { sp = (const float4*)s0; dp = (ushort4*)d0; j = i; }
  else            { sp = (const float4*)s1; dp = (ushort4*)d1; j = i - n4each; }
  float4 v = sp[j];
  ushort4 o;
  o.x = f2bf(v.x); o.y = f2bf(v.y); o.z = f2bf(v.z); o.w = f2bf(v.w);
  dp[j] = o;
}

// ============ FUSED PATH: 256x256 8-wave counted-vmcnt GEMM + scan ==========
// R3: pipelined frag reads with THREE frag sets (af0/af1 dbuf + single bfv).
// bfv is re-loaded via tail-reads issued AFTER its last consuming MFMA
// (end of p1: ks1; end of p3: next-tile ks0), so no in-phase DS stall and
// frag regs = 48 (vs R2's 64, which spilled at the 256-reg/wave cap).
// vmcnt waits only at p1(8) and p3(8); lgkmcnt(4) per phase.  Ledger:
//  A(t)k1 staged (t-1)p0 = 5th-newest pair at p1's wait(8)  -> covered
//  A(t+1)k0 / B(t+1)k0 staged (t-1)p2/p1 = 5th/6th-newest at p3's wait(8)
//  B(t)k1 staged (t-2)p3, older                              -> covered
// Region overwrites (SUNIT t+2 into the buffer being read) all land >=1
// barrier after the counted lgkm retiring the last read of that region.

__device__ __forceinline__ void gload16(const unsigned short* g,
                                        unsigned short* l) {
  __builtin_amdgcn_global_load_lds(
      (const __attribute__((address_space(1))) unsigned int*)g,
      (__attribute__((address_space(3))) unsigned int*)l, 16, 0, 0);
}

#define WAITVM(n) asm volatile("s_waitcnt vmcnt(" #n ")" ::: "memory")
#define WAITLGKM(n) asm volatile("s_waitcnt lgkmcnt(" #n ")" ::: "memory")
#define SCHEDB() __builtin_amdgcn_sched_barrier(0)

__global__ __launch_bounds__(512, 2) void gemm_scan256_kernel(
    const unsigned short* __restrict__ A,
    const unsigned short* __restrict__ Bm,
    const float* __restrict__ bias,
    const float* __restrict__ freq,
    const float* __restrict__ damp,
    unsigned short* __restrict__ zpart,
    float* __restrict__ chunkS,
    float* __restrict__ chunkV) {
  extern __shared__ __align__(16) unsigned short smem[];   // 128 KiB

  const int tid  = threadIdx.x;
  const int lane = tid & 63;
  const int w    = tid >> 6;     // wave 0..7
  const int wr   = w >> 2;       // 0..1  (M half)
  const int wc   = w & 3;        // 0..3  (N quarter)
  const int q    = lane >> 4;
  const int lm   = lane & 15;

  // XCD-chunked bijective swizzle: 256 blocks, 8 XCDs, 32 blocks each.
  const int bid = blockIdx.x;
  const int wg  = (bid & 7) * 32 + (bid >> 3);
  const int tm  = wg >> 4;       // tile row 0..15
  const int tn  = wg & 15;       // tile col 0..15
  const int bM  = tm * 256;
  const int bN  = tn * 256;

  // ---- staging addressing (per-thread, loop-invariant) ----
  const int srow  = w * 16 + (lane >> 2);
  const int sslot = (lane & 3) ^ ((lane >> 3) & 3);
  const unsigned short* gA = A  + (size_t)(bM + srow) * KDIM + sslot * 8;
  const unsigned short* gB = Bm + (size_t)(bN + srow) * KDIM + sslot * 8;
  const int ldst = w * 512 + lane * 8;        // shorts within unit

#define SUNIT(mat, u, ks, rh)                                              \
  gload16((mat ? gB : gA) + (size_t)(rh) * 128 * KDIM + (u) * 64 + (ks) * 32, \
          smem + ((u) & 1) * 32768 + (mat) * 16384 + (ks) * 8192 +         \
              (rh) * 4096 + ldst)

  // ---- ds_read frag addressing ----
  const int flane = (lm >> 1) & 3;
  const int aoff  = (wr * 128 + lm) * 32 + ((q ^ flane) * 8);
  const int boff  = 16384 + (wc * 64 + lm) * 32 + ((q ^ flane) * 8);

  f32x4 acc[8][4];
#pragma unroll
  for (int i = 0; i < 8; i++)
#pragma unroll
    for (int j = 0; j < 4; j++) acc[i][j] = (f32x4){0.f, 0.f, 0.f, 0.f};

  // ---- prologue: 7 stage-pairs (FIFO order is the vmcnt ledger) ----
  SUNIT(1, 0, 0, 0); SUNIT(1, 0, 0, 1);   // P1: B0 ks0
  SUNIT(0, 0, 0, 0); SUNIT(0, 0, 0, 1);   // P2: A0 ks0
  SUNIT(1, 0, 1, 0); SUNIT(1, 0, 1, 1);   // P3: B0 ks1
  SUNIT(0, 0, 1, 0); SUNIT(0, 0, 1, 1);   // P4: A0 ks1
  SUNIT(1, 1, 0, 0); SUNIT(1, 1, 0, 1);   // P5: B1 ks0
  SUNIT(0, 1, 0, 0); SUNIT(0, 1, 0, 1);   // P6: A1 ks0
  SUNIT(1, 1, 1, 0); SUNIT(1, 1, 1, 1);   // P7: B1 ks1

#define LDA4(dst, BUFO, KS, MH)                                            \
  _Pragma("unroll") for (int m = 0; m < 4; ++m) dst[m] =                   \
      *(const bf16x8*)&smem[(BUFO) + (KS) + (MH) + aoff + m * 512]
#define LDB4(dst, BUFO, KS)                                                \
  _Pragma("unroll") for (int n = 0; n < 4; ++n) dst[n] =                   \
      *(const bf16x8*)&smem[(BUFO) + (KS) + boff + n * 512]
#define MFMA16(AF, BF, MB)                                                 \
  __builtin_amdgcn_s_setprio(1);                                          \
  _Pragma("unroll") for (int m = 0; m < 4; ++m)                            \
      _Pragma("unroll") for (int n = 0; n < 4; ++n)                        \
          acc[(MB) + m][n] = __builtin_amdgcn_mfma_f32_16x16x32_bf16(      \
              AF[m], BF[n], acc[(MB) + m][n], 0, 0, 0);                    \
  __builtin_amdgcn_s_setprio(0)

  bf16x8 af0[4], af1[4], bfv[4];

  // prologue frags for tile0.p0 (wait(10): oldest 4 loads = P1,P2 landed)
  WAITVM(10);
  __builtin_amdgcn_s_barrier();
  LDA4(af0, 0, 0, 0);       // A0 ks0 mlo
  LDB4(bfv, 0, 0);          // B0 ks0

#pragma unroll 2
  for (int t = 0; t < TILES; ++t) {
    const int bufo  = (t & 1) * 32768;
    const int nbufo = ((t + 1) & 1) * 32768;

    // ---- p0: MFMA(ks0,mlo)[af0,bfv]; pre-read af1 = ks0 mhi ----
    __builtin_amdgcn_s_barrier();
    if (t + 1 < TILES) { SUNIT(0, t + 1, 1, 0); SUNIT(0, t + 1, 1, 1); }
    LDA4(af1, bufo, 0, 2048);
    WAITLGKM(4); SCHEDB();
    MFMA16(af0, bfv, 0);

    // ---- p1: MFMA(ks0,mhi)[af1,bfv]; pre-read af0 = ks1 mlo;
    //          tail-read bfv <- B ks1 (after last bfv-ks0 use) ----
    if (t < TILES - 1) { WAITVM(8); } else { WAITVM(0); }
    __builtin_amdgcn_s_barrier();
    if (t + 2 < TILES) { SUNIT(1, t + 2, 0, 0); SUNIT(1, t + 2, 0, 1); }
    LDA4(af0, bufo, 8192, 0);
    WAITLGKM(4); SCHEDB();
    MFMA16(af1, bfv, 4);
    LDB4(bfv, bufo, 8192);     // data covered by this phase's WAITVM

    // ---- p2: MFMA(ks1,mlo)[af0,bfv]; pre-read af1 = ks1 mhi ----
    __builtin_amdgcn_s_barrier();
    if (t + 2 < TILES) { SUNIT(0, t + 2, 0, 0); SUNIT(0, t + 2, 0, 1); }
    LDA4(af1, bufo, 8192, 2048);
    WAITLGKM(4); SCHEDB();
    MFMA16(af0, bfv, 0);

    // ---- p3: MFMA(ks1,mhi)[af1,bfv]; pre-read af0 = next ks0 mlo;
    //          tail-read bfv <- next B ks0 ----
    if (t < TILES - 2) { WAITVM(8); }
    else if (t == TILES - 2) { WAITVM(4); }   // stages skipped -> tighter
    __builtin_amdgcn_s_barrier();
    if (t + 2 < TILES) { SUNIT(1, t + 2, 1, 0); SUNIT(1, t + 2, 1, 1); }
    if (t + 1 < TILES) {
      LDA4(af0, nbufo, 0, 0);
      WAITLGKM(4); SCHEDB();
      MFMA16(af1, bfv, 4);
      LDB4(bfv, nbufo, 0);     // data covered by this phase's WAITVM
    } else {
      WAITLGKM(0); SCHEDB();
      MFMA16(af1, bfv, 4);
    }
  }
#undef LDA4
#undef LDB4
#undef MFMA16
#undef SUNIT

  // ================= epilogue: transpose + chunk scan =================
  __syncthreads();   // drains lgkm/vm; LDS reusable as sT[256][256] bf16

  // acc -> sT with bias; col swizzle col' = col ^ (q<<4) -> conflict-free
#pragma unroll
  for (int n = 0; n < 4; ++n) {
    const float bz = bias[bN + wc * 64 + n * 16 + lm];
#pragma unroll
    for (int M = 0; M < 8; ++M)
#pragma unroll
      for (int rr = 0; rr < 4; ++rr) {
        const int row = wr * 128 + M * 16 + q * 4 + rr;
        const int col = wc * 64 + ((n ^ q) * 16) + lm;   // swizzled store
        smem[row * 256 + col] = f2bf(acc[M][n][rr] + bz);
      }
  }
  __syncthreads();

  // lane scans a column over two 64-row chunks (zero init), in-place s store
  {
    const int col  = tid & 255;
    const int ch0  = (tid >> 8) * 2;
    const int gcol = bN + col;
    const float om  = TWO_PI_F * freq[gcol];
    const float osq = om * om;
    const float dp  = damp[gcol];
#pragma unroll
    for (int cc = 0; cc < 2; ++cc) {
      const int ch = ch0 + cc;
      float s = 0.f, v = 0.f;
#pragma unroll 8
      for (int i = 0; i < CL; ++i) {
        const int row = ch * 64 + i;
        const int idx = row * 256 + (col ^ (((i >> 2) & 3) << 4));
        float f = bf2f(smem[idx]);
        v += (-osq * s - dp * v + f) * DT;
        s += v * DT;
        smem[idx] = f2bf(s);
      }
      const int chunk = tm * 4 + ch;
      chunkS[chunk * NDIM + gcol] = s;
      chunkV[chunk * NDIM + gcol] = v;
    }
  }
  __syncthreads();

  // coalesced writeback of the 256x256 bf16 zpart tile (un-swizzling groups)
#pragma unroll
  for (int k = 0; k < 16; ++k) {
    const int slot = tid + 512 * k;
    const int row  = slot >> 5;
    const int grp  = slot & 31;
    const int sgrp = grp ^ (((row >> 2) & 3) << 1);
    *(uint4*)&zpart[(size_t)(bM + row) * NDIM + bN + grp * 8] =
        *(const uint4*)&smem[row * 256 + sgrp * 8];
  }
}

// ---- pass2 IN-PLACE: chunk partials -> carries (same array, 2 MB, ~2 us) ---
__global__ void scan_pass2_inplace(float* __restrict__ chunkS,
                                   float* __restrict__ chunkV,
                                   const float* __restrict__ freq,
                                   const float* __restrict__ damp) {
  int n = blockIdx.x * blockDim.x + threadIdx.x;     // 0..NDIM-1
  float om = TWO_PI_F * freq[n];
  float osq = om * om;
  float dp = damp[n];
  float a00 = 1.f - osq * DT * DT, a01 = DT * (1.f - dp * DT);
  float a10 = -osq * DT,           a11 = 1.f - dp * DT;
#pragma unroll
  for (int i = 0; i < 6; i++) {                      // M^64 by squaring
    float b00 = a00 * a00 + a01 * a10;
    float b01 = a00 * a01 + a01 * a11;
    float b10 = a10 * a00 + a11 * a10;
    float b11 = a10 * a01 + a11 * a11;
    a00 = b00; a01 = b01; a10 = b10; a11 = b11;
  }
  float cs = 0.f, cv = 0.f;
#pragma unroll 8
  for (int c = 0; c < CH; c++) {
    float ls = chunkS[c * NDIM + n];                 // read before overwrite
    float lv = chunkV[c * NDIM + n];
    chunkS[c * NDIM + n] = cs;
    chunkV[c * NDIM + n] = cv;
    float ns = a00 * cs + a01 * cv + ls;
    float nv = a10 * cs + a11 * cv + lv;
    cs = ns; cv = nv;
  }
}

// ---- kernel 3: carry load + homogeneous replay + osc/clip, fp32 out ----
__global__ void scan_out_carry4(const unsigned short* __restrict__ zpart,
                                const float* __restrict__ amp,
                                const float* __restrict__ freq,
                                const float* __restrict__ phase,
                                const float* __restrict__ damp,
                                const float* __restrict__ carryS,
                                const float* __restrict__ carryV,
                                float* __restrict__ out) {
  int gid = blockIdx.x * blockDim.x + threadIdx.x;   // 0 .. CH*4*NDIM/4
  int n4 = gid & (NDIM / 4 - 1);
  int cq = gid >> 10;            // chunk*4 + quarter
  int c  = cq >> 2;
  int qq = cq & 3;
  int n  = n4 * 4;

  float4 fr = *(const float4*)&freq[n];
  float4 dv = *(const float4*)&damp[n];
  float4 am = *(const float4*)&amp[n];
  float4 ph = *(const float4*)&phase[n];
  float omv[4] = {TWO_PI_F * fr.x, TWO_PI_F * fr.y, TWO_PI_F * fr.z, TWO_PI_F * fr.w};
  float dpv[4] = {dv.x, dv.y, dv.z, dv.w};
  float amv[4] = {am.x, am.y, am.z, am.w};
  float phv[4] = {ph.x, ph.y, ph.z, ph.w};
  float m00[4], m01[4], m10[4], m11[4], osc[4];
#pragma unroll
  for (int j = 0; j < 4; j++) {
    float osq = omv[j] * omv[j];
    m00[j] = 1.f - osq * DT * DT;  m01[j] = DT * (1.f - dpv[j] * DT);
    m10[j] = -osq * DT;            m11[j] = 1.f - dpv[j] * DT;
    osc[j] = amv[j] * sinf(omv[j] * DT + phv[j]);    // t = DT
  }

  // P = M^16 by squaring; J = P^qq; h = J * carry
  float4 csv = *(const float4*)&carryS[c * NDIM + n];
  float4 cvv = *(const float4*)&carryV[c * NDIM + n];
  float cs[4] = {csv.x, csv.y, csv.z, csv.w};
  float cv[4] = {cvv.x, cvv.y, cvv.z, cvv.w};
  float hs[4], hv[4];
#pragma unroll
  for (int j = 0; j < 4; j++) {
    float p00 = m00[j], p01 = m01[j], p10 = m10[j], p11 = m11[j];
#pragma unroll
    for (int k = 0; k < 4; k++) {                    // M^16
      float b00 = p00 * p00 + p01 * p10;
      float b01 = p00 * p01 + p01 * p11;
      float b10 = p10 * p00 + p11 * p10;
      float b11 = p10 * p01 + p11 * p11;
      p00 = b00; p01 = b01; p10 = b10; p11 = b11;
    }
    float j00 = 1.f, j01 = 0.f, j10 = 0.f, j11 = 1.f;
    for (int k = 0; k < qq; k++) {                   // wave-uniform qq
      float b00 = j00 * p00 + j01 * p10;
      float b01 = j00 * p01 + j01 * p11;
      float b10 = j10 * p00 + j11 * p10;
      float b11 = j10 * p01 + j11 * p11;
      j00 = b00; j01 = b01; j10 = b10; j11 = b11;
    }
    hs[j] = j00 * cs[j] + j01 * cv[j];
    hv[j] = j10 * cs[j] + j11 * cv[j];
  }

  const size_t r0 = (size_t)c * CL + qq * 16;
  const unsigned short* zp = zpart + r0 * NDIM + n;
  float* op = out + r0 * NDIM + n;
#pragma unroll 4
  for (int i = 0; i < 16; ++i) {
    ushort4 zv = *(const ushort4*)&zp[(size_t)i * NDIM];
    float z[4] = {bf2f(zv.x), bf2f(zv.y), bf2f(zv.z), bf2f(zv.w)};
    float o[4];
#pragma unroll
    for (int j = 0; j < 4; j++) {
      float t = m00[j] * hs[j] + m01[j] * hv[j];     // h = M h
      float u = m10[j] * hs[j] + m11[j] * hv[j];
      hs[j] = t; hv[j] = u;
      o[j] = fminf(1.f, fmaxf(-1.f, hs[j] + z[j] + osc[j]));
    }
    *(float4*)&op[(size_t)i * NDIM] = (float4){o[0], o[1], o[2], o[3]};
  }
}

// ============ FALLBACK PATH: exact round-7 pipeline (64 MiB ws) ============
__global__ __launch_bounds__(256, 2) void gemm_bt_kernel(
    const unsigned short* __restrict__ A,
    const unsigned short* __restrict__ Bm,
    const float* __restrict__ bias,
    unsigned short* __restrict__ C) {
  __shared__ __align__(16) unsigned short sA[128 * 32];
  __shared__ __align__(16) unsigned short sB[128 * 32];

  const int tid  = threadIdx.x;
  const int lane = tid & 63;
  const int wave = tid >> 6;
  const int wr = wave >> 1;
  const int wc = wave & 1;
  const int q  = lane >> 4;
  const int lm = lane & 15;

  const int bM = blockIdx.x * 128;
  const int bN = blockIdx.y * 128;

  f32x4 acc[4][4];
#pragma unroll
  for (int i = 0; i < 4; i++)
#pragma unroll
    for (int j = 0; j < 4; j++) acc[i][j] = (f32x4){0.f, 0.f, 0.f, 0.f};

  const int idx0 = tid;
  const int idx1 = tid + 256;
  const int r0 = idx0 >> 2, g0 = idx0 & 3;
  const int r1 = idx1 >> 2, g1 = idx1 & 3;
  const int dst0 = r0 * 32 + ((g0 ^ ((r0 >> 1) & 3)) * 8);
  const int dst1 = r1 * 32 + ((g1 ^ ((r1 >> 1) & 3)) * 8);
  const unsigned short* gA0 = A  + (size_t)(bM + r0) * KDIM + g0 * 8;
  const unsigned short* gA1 = A  + (size_t)(bM + r1) * KDIM + g1 * 8;
  const unsigned short* gB0 = Bm + (size_t)(bN + r0) * KDIM + g0 * 8;
  const unsigned short* gB1 = Bm + (size_t)(bN + r1) * KDIM + g1 * 8;
  const int rq = (q ^ ((lm >> 1) & 3)) * 8;

  for (int k0 = 0; k0 < KDIM; k0 += 32) {
    uint4 av0 = *(const uint4*)(gA0 + k0);
    uint4 av1 = *(const uint4*)(gA1 + k0);
    uint4 bv0 = *(const uint4*)(gB0 + k0);
    uint4 bv1 = *(const uint4*)(gB1 + k0);
    __syncthreads();
    *(uint4*)&sA[dst0] = av0;
    *(uint4*)&sA[dst1] = av1;
    *(uint4*)&sB[dst0] = bv0;
    *(uint4*)&sB[dst1] = bv1;
    __syncthreads();

    bf16x8 af[4], bfr[4];
#pragma unroll
    for (int mt = 0; mt < 4; mt++)
      af[mt]  = *(const bf16x8*)&sA[(wr * 64 + mt * 16 + lm) * 32 + rq];
#pragma unroll
    for (int nt = 0; nt < 4; nt++)
      bfr[nt] = *(const bf16x8*)&sB[(wc * 64 + nt * 16 + lm) * 32 + rq];

#pragma unroll
    for (int mt = 0; mt < 4; mt++)
#pragma unroll
      for (int nt = 0; nt < 4; nt++)
        acc[mt][nt] = __builtin_amdgcn_mfma_f32_16x16x32_bf16(
            af[mt], bfr[nt], acc[mt][nt], 0, 0, 0);
  }

#pragma unroll
  for (int nt = 0; nt < 4; nt++) {
    const int col = bN + wc * 64 + nt * 16 + lm;
    const float bz = bias[col];
#pragma unroll
    for (int mt = 0; mt < 4; mt++) {
      const int row0 = bM + wr * 64 + mt * 16 + q * 4;
#pragma unroll
      for (int r = 0; r < 4; r++)
        C[(size_t)(row0 + r) * NDIM + col] = f2bf(acc[mt][nt][r] + bz);
    }
  }
}

__global__ void scan_pass1(const unsigned short* __restrict__ force,
                           const float* __restrict__ freq,
                           const float* __restrict__ damp,
                           float* __restrict__ chunkS,
                           float* __restrict__ chunkV) {
  int gid = blockIdx.x * blockDim.x + threadIdx.x;
  int n4 = gid & (NDIM / 4 - 1);
  int c  = gid >> 10;
  int n  = n4 * 4;
  float4 fr = *(const float4*)&freq[n];
  float4 dv = *(const float4*)&damp[n];
  float osq[4] = {TWO_PI_F * fr.x, TWO_PI_F * fr.y, TWO_PI_F * fr.z, TWO_PI_F * fr.w};
  float dp[4]  = {dv.x, dv.y, dv.z, dv.w};
  float s[4] = {0.f, 0.f, 0.f, 0.f}, v[4] = {0.f, 0.f, 0.f, 0.f};
#pragma unroll
  for (int j = 0; j < 4; j++) osq[j] *= osq[j];
  const unsigned short* fp = force + (size_t)c * CL * NDIM + n;
#pragma unroll 4
  for (int i = 0; i < CL; i++) {
    ushort4 fv = *(const ushort4*)&fp[(size_t)i * NDIM];
    float f[4] = {bf2f(fv.x), bf2f(fv.y), bf2f(fv.z), bf2f(fv.w)};
#pragma unroll
    for (int j = 0; j < 4; j++) {
      float a = -osq[j] * s[j] - dp[j] * v[j] + f[j];
      v[j] += a * DT;
      s[j] += v[j] * DT;
    }
  }
  *(float4*)&chunkS[c * NDIM + n] = (float4){s[0], s[1], s[2], s[3]};
  *(float4*)&chunkV[c * NDIM + n] = (float4){v[0], v[1], v[2], v[3]};
}

__global__ void scan_pass2(const float* __restrict__ chunkS,
                           const float* __restrict__ chunkV,
                           const float* __restrict__ freq,
                           const float* __restrict__ damp,
                           float* __restrict__ carryS,
                           float* __restrict__ carryV) {
  int n = blockIdx.x * blockDim.x + threadIdx.x;
  float om = TWO_PI_F * freq[n];
  float osq = om * om;
  float dp = damp[n];
  float a00 = 1.f - osq * DT * DT, a01 = DT * (1.f - dp * DT);
  float a10 = -osq * DT,           a11 = 1.f - dp * DT;
#pragma unroll
  for (int i = 0; i < 6; i++) {
    float b00 = a00 * a00 + a01 * a10;
    float b01 = a00 * a01 + a01 * a11;
    float b10 = a10 * a00 + a11 * a10;
    float b11 = a10 * a01 + a11 * a11;
    a00 = b00; a01 = b01; a10 = b10; a11 = b11;
  }
  float cs = 0.f, cv = 0.f;
#pragma unroll 8
  for (int c = 0; c < CH; c++) {
    carryS[c * NDIM + n] = cs;
    carryV[c * NDIM + n] = cv;
    float ls = chunkS[c * NDIM + n];
    float lv = chunkV[c * NDIM + n];
    float ns = a00 * cs + a01 * cv + ls;
    float nv = a10 * cs + a11 * cv + lv;
    cs = ns; cv = nv;
  }
}

__global__ void scan_pass3(const unsigned short* __restrict__ force,
                           const float* __restrict__ amp,
                           const float* __restrict__ freq,
                           const float* __restrict__ phase,
                           const float* __restrict__ damp,
                           const float* __restrict__ carryS,
                           const float* __restrict__ carryV,
                           float* __restrict__ out) {
  int gid = blockIdx.x * blockDim.x + threadIdx.x;
  int n4 = gid & (NDIM / 4 - 1);
  int c  = gid >> 10;
  int n  = n4 * 4;
  float4 fr = *(const float4*)&freq[n];
  float4 dv = *(const float4*)&damp[n];
  float4 am = *(const float4*)&amp[n];
  float4 ph = *(const float4*)&phase[n];
  float om[4] = {TWO_PI_F * fr.x, TWO_PI_F * fr.y, TWO_PI_F * fr.z, TWO_PI_F * fr.w};
  float dp[4] = {dv.x, dv.y, dv.z, dv.w};
  float osq[4], osc[4], s[4], v[4];
  float amv[4] = {am.x, am.y, am.z, am.w};
  float phv[4] = {ph.x, ph.y, ph.z, ph.w};
#pragma unroll
  for (int j = 0; j < 4; j++) {
    osq[j] = om[j] * om[j];
    osc[j] = amv[j] * sinf(om[j] * DT + phv[j]);
  }
  float4 csv = *(const float4*)&carryS[c * NDIM + n];
  float4 cvv = *(const float4*)&carryV[c * NDIM + n];
  s[0] = csv.x; s[1] = csv.y; s[2] = csv.z; s[3] = csv.w;
  v[0] = cvv.x; v[1] = cvv.y; v[2] = cvv.z; v[3] = cvv.w;
  const unsigned short* fp = force + (size_t)c * CL * NDIM + n;
  float* op = out + (size_t)c * CL * NDIM + n;
#pragma unroll 4
  for (int i = 0; i < CL; i++) {
    ushort4 fv = *(const ushort4*)&fp[(size_t)i * NDIM];
    float f[4] = {bf2f(fv.x), bf2f(fv.y), bf2f(fv.z), bf2f(fv.w)};
    float o[4];
#pragma unroll
    for (int j = 0; j < 4; j++) {
      float a = -osq[j] * s[j] - dp[j] * v[j] + f[j];
      v[j] += a * DT;
      s[j] += v[j] * DT;
      o[j] = fminf(1.f, fmaxf(-1.f, s[j] + osc[j]));
    }
    *(float4*)&op[(size_t)i * NDIM] = (float4){o[0], o[1], o[2], o[3]};
  }
}

// ---------------- launch ----------------
extern "C" void kernel_launch(void* const* d_in, const int* in_sizes, int n_in,
                              void* d_out, int out_size, void* d_ws, size_t ws_size,
                              hipStream_t stream) {
  const float* x     = (const float*)d_in[0];
  const float* W     = (const float*)d_in[1];
  const float* bias  = (const float*)d_in[2];
  const float* amp   = (const float*)d_in[3];
  const float* freq  = (const float*)d_in[4];
  const float* phase = (const float*)d_in[5];
  const float* damp  = (const float*)d_in[6];

  const size_t MiB = 1024 * 1024;
  const int n4each = MDIM * KDIM / 4;

  if (ws_size >= 66 * MiB) {
    // fused path (66 MiB):
    // xbf[0,16Mi) wbf[16,32Mi) zpart[32,64Mi) chunkS/V[64,66Mi)
    unsigned short* xbf   = (unsigned short*)d_ws;
    unsigned short* wbf   = xbf + (size_t)MDIM * KDIM;
    unsigned short* zpart = wbf + (size_t)NDIM * KDIM;
    float* chunkS = (float*)((char*)d_ws + 64 * MiB);
    float* chunkV = chunkS + CH * NDIM;

    static bool attr_done = false;
    if (!attr_done) {
      (void)hipFuncSetAttribute((const void*)gemm_scan256_kernel,
                                hipFuncAttributeMaxDynamicSharedMemorySize,
                                131072);
      attr_done = true;
    }

    cast2_bf16_kernel<<<(2 * n4each + 255) / 256, 256, 0, stream>>>(
        x, xbf, W, wbf, n4each);
    gemm_scan256_kernel<<<dim3(256), dim3(512), 131072, stream>>>(
        xbf, wbf, bias, freq, damp, zpart, chunkS, chunkV);
    scan_pass2_inplace<<<NDIM / 256, 256, 0, stream>>>(chunkS, chunkV,
                                                       freq, damp);
    // chunkS/V now hold carries (in-place)
    scan_out_carry4<<<CH * 4 * NDIM / 4 / 256, 256, 0, stream>>>(
        zpart, amp, freq, phase, damp, chunkS, chunkV, (float*)d_out);
  } else {
    // fallback: exact round-7 pipeline (proven, 64 MiB)
    dim3 gg(MDIM / 128, NDIM / 128);
    unsigned short* xbf   = (unsigned short*)d_ws;
    unsigned short* wbf   = xbf + (size_t)MDIM * KDIM;
    unsigned short* force = wbf + (size_t)NDIM * KDIM;
    float* chunkS = (float*)d_ws;            // aliases xbf: dead after GEMM
    float* chunkV = chunkS + CH * NDIM;
    float* carryS = chunkV + CH * NDIM;
    float* carryV = carryS + CH * NDIM;

    cast2_bf16_kernel<<<(2 * n4each + 255) / 256, 256, 0, stream>>>(
        x, xbf, W, wbf, n4each);
    gemm_bt_kernel<<<gg, 256, 0, stream>>>(xbf, wbf, bias, force);
    scan_pass1<<<CH * NDIM / 4 / 256, 256, 0, stream>>>(force, freq, damp,
                                                        chunkS, chunkV);
    scan_pass2<<<NDIM / 256, 256, 0, stream>>>(chunkS, chunkV, freq, damp,
                                               carryS, carryV);
    scan_pass3<<<CH * NDIM / 4 / 256, 256, 0, stream>>>(
        force, amp, freq, phase, damp, carryS, carryV, (float*)d_out);
  }
}

// Round 4
// 205.065 us; speedup vs baseline: 1.5354x; 1.5354x over previous
//
#include <hip/hip_runtime.h>
#include <hip/hip_bf16.h>
#include <math.h>

// Problem constants (B,D,N from reference)
#define MDIM 4096   // batch rows
#define KDIM 2048   // feature dim D
#define NDIM 4096   // output dim N
#define DT   0.01f
#define TWO_PI_F 6.283185307179586f
#define CH 64       // scan chunks
#define CL 64       // steps per chunk  (CH*CL == MDIM)
#define TILES (KDIM / 64)   // 32 K-tiles of BK=64

typedef __attribute__((ext_vector_type(8))) short bf16x8;
typedef __attribute__((ext_vector_type(4))) float f32x4;

__device__ __forceinline__ unsigned short f2bf(float f) {
  unsigned int u = __float_as_uint(f);
  u += 0x7FFFu + ((u >> 16) & 1u);           // round-to-nearest-even
  return (unsigned short)(u >> 16);
}
__device__ __forceinline__ float bf2f(unsigned short u) {
  return __uint_as_float(((unsigned int)u) << 16);
}

// -------- fused cast fp32 -> bf16 for x and W (both 8M floats) --------
__global__ void cast2_bf16_kernel(const float* __restrict__ s0,
                                  unsigned short* __restrict__ d0,
                                  const float* __restrict__ s1,
                                  unsigned short* __restrict__ d1,
                                  int n4each) {
  int i = blockIdx.x * blockDim.x + threadIdx.x;
  const float4* sp;
  ushort4* dp;
  int j;
  if (i < n4each) { sp = (const float4*)s0; dp = (ushort4*)d0; j = i; }
  else            { sp = (const float4*)s1; dp = (ushort4*)d1; j = i - n4each; }
  float4 v = sp[j];
  ushort4 o;
  o.x = f2bf(v.x); o.y = f2bf(v.y); o.z = f2bf(v.z); o.w = f2bf(v.w);
  dp[j] = o;
}

// ============ FUSED PATH: 256x256 8-wave counted-vmcnt GEMM + scan ==========
// R4: TAIL-READ pipelining with ZERO extra registers.  Each phase:
//   barrier; SUNIT pair; lgkmcnt(0); sched_barrier; setprio(1); 16xMFMA;
//   setprio(0); tail ds_reads for NEXT phase into the SAME af/bfr regs;
//   sched_barrier
// WAR on af/bfr is safe: MFMA operands are latched at issue, tail ds_reads
// issue after all 16 MFMAs (program order).  Read latency hides under the
// next barrier-wait + other waves' staggered MFMAs (breaks the R1 lockstep
// where all 16 waves/CU did DS and MFMA in alternating bursts).
// Hazard ledger (re-derived, R1's vmcnt positions unchanged):
//  p1 tail A(t)k1 : 9th-newest pair at p1's WAITVM(8)  -> resident
//  p1 tail B(t)k1 : staged (t-2)p3, 11th at p1's wait  -> resident
//  p2 tail A(t)k1mhi: same region                       -> resident
//  p3 tail A/B(t+1)k0: 9th-12th at p3's WAITVM(8)       -> resident
//  Region overwrites (t+2 SUNITs into buffer-t) land >=1 barrier after the
//  lgkmcnt(0) retiring the last read of that region (all 4 regions checked).

__device__ __forceinline__ void gload16(const unsigned short* g,
                                        unsigned short* l) {
  __builtin_amdgcn_global_load_lds(
      (const __attribute__((address_space(1))) unsigned int*)g,
      (__attribute__((address_space(3))) unsigned int*)l, 16, 0, 0);
}

#define WAITVM(n) asm volatile("s_waitcnt vmcnt(" #n ")" ::: "memory")
#define WAITLGKM(n) asm volatile("s_waitcnt lgkmcnt(" #n ")" ::: "memory")
#define SCHEDB() __builtin_amdgcn_sched_barrier(0)

__global__ __launch_bounds__(512, 2) void gemm_scan256_kernel(
    const unsigned short* __restrict__ A,
    const unsigned short* __restrict__ Bm,
    const float* __restrict__ bias,
    const float* __restrict__ freq,
    const float* __restrict__ damp,
    unsigned short* __restrict__ zpart,
    float* __restrict__ chunkS,
    float* __restrict__ chunkV) {
  extern __shared__ __align__(16) unsigned short smem[];   // 128 KiB

  const int tid  = threadIdx.x;
  const int lane = tid & 63;
  const int w    = tid >> 6;     // wave 0..7
  const int wr   = w >> 2;       // 0..1  (M half)
  const int wc   = w & 3;        // 0..3  (N quarter)
  const int q    = lane >> 4;
  const int lm   = lane & 15;

  // XCD-chunked bijective swizzle: 256 blocks, 8 XCDs, 32 blocks each.
  const int bid = blockIdx.x;
  const int wg  = (bid & 7) * 32 + (bid >> 3);
  const int tm  = wg >> 4;       // tile row 0..15
  const int tn  = wg & 15;       // tile col 0..15
  const int bM  = tm * 256;
  const int bN  = tn * 256;

  // ---- staging addressing (per-thread, loop-invariant) ----
  const int srow  = w * 16 + (lane >> 2);
  const int sslot = (lane & 3) ^ ((lane >> 3) & 3);
  const unsigned short* gA = A  + (size_t)(bM + srow) * KDIM + sslot * 8;
  const unsigned short* gB = Bm + (size_t)(bN + srow) * KDIM + sslot * 8;
  const int ldst = w * 512 + lane * 8;        // shorts within unit

#define SUNIT(mat, u, ks, rh)                                              \
  gload16((mat ? gB : gA) + (size_t)(rh) * 128 * KDIM + (u) * 64 + (ks) * 32, \
          smem + ((u) & 1) * 32768 + (mat) * 16384 + (ks) * 8192 +         \
              (rh) * 4096 + ldst)

  // ---- ds_read frag addressing ----
  const int flane = (lm >> 1) & 3;
  const int aoff  = (wr * 128 + lm) * 32 + ((q ^ flane) * 8);
  const int boff  = 16384 + (wc * 64 + lm) * 32 + ((q ^ flane) * 8);

  f32x4 acc[8][4];
#pragma unroll
  for (int i = 0; i < 8; i++)
#pragma unroll
    for (int j = 0; j < 4; j++) acc[i][j] = (f32x4){0.f, 0.f, 0.f, 0.f};

  // ---- prologue: 7 stage-pairs (FIFO order is the vmcnt ledger) ----
  SUNIT(1, 0, 0, 0); SUNIT(1, 0, 0, 1);   // P1: B0 ks0
  SUNIT(0, 0, 0, 0); SUNIT(0, 0, 0, 1);   // P2: A0 ks0
  SUNIT(1, 0, 1, 0); SUNIT(1, 0, 1, 1);   // P3: B0 ks1
  SUNIT(0, 0, 1, 0); SUNIT(0, 0, 1, 1);   // P4: A0 ks1
  SUNIT(1, 1, 0, 0); SUNIT(1, 1, 0, 1);   // P5: B1 ks0
  SUNIT(0, 1, 0, 0); SUNIT(0, 1, 0, 1);   // P6: A1 ks0
  SUNIT(1, 1, 1, 0); SUNIT(1, 1, 1, 1);   // P7: B1 ks1

#define LDA4(dst, BUFO, KS, MH)                                            \
  _Pragma("unroll") for (int m = 0; m < 4; ++m) dst[m] =                   \
      *(const bf16x8*)&smem[(BUFO) + (KS) + (MH) + aoff + m * 512]
#define LDB4(dst, BUFO, KS)                                                \
  _Pragma("unroll") for (int n = 0; n < 4; ++n) dst[n] =                   \
      *(const bf16x8*)&smem[(BUFO) + (KS) + boff + n * 512]
#define MFMA16(AF, BF, MB)                                                 \
  __builtin_amdgcn_s_setprio(1);                                          \
  _Pragma("unroll") for (int m = 0; m < 4; ++m)                            \
      _Pragma("unroll") for (int n = 0; n < 4; ++n)                        \
          acc[(MB) + m][n] = __builtin_amdgcn_mfma_f32_16x16x32_bf16(      \
              AF[m], BF[n], acc[(MB) + m][n], 0, 0, 0);                    \
  __builtin_amdgcn_s_setprio(0)

  bf16x8 af[4], bfr[4];

  // prologue frags for tile0.p0 (wait(10): oldest 4 loads = P1,P2 landed)
  WAITVM(10);
  __builtin_amdgcn_s_barrier();
  LDA4(af, 0, 0, 0);        // A0 ks0 mlo
  LDB4(bfr, 0, 0);          // B0 ks0
  SCHEDB();

#pragma unroll 2
  for (int t = 0; t < TILES; ++t) {
    const int bufo  = (t & 1) * 32768;
    const int nbufo = ((t + 1) & 1) * 32768;

    // ---- p0: MFMA(ks0,mlo); tail: af <- ks0 mhi ----
    __builtin_amdgcn_s_barrier();
    if (t + 1 < TILES) { SUNIT(0, t + 1, 1, 0); SUNIT(0, t + 1, 1, 1); }
    WAITLGKM(0); SCHEDB();
    MFMA16(af, bfr, 0);
    LDA4(af, bufo, 0, 2048);
    SCHEDB();

    // ---- p1: MFMA(ks0,mhi); tail: af <- ks1 mlo, bfr <- B ks1 ----
    if (t < TILES - 1) { WAITVM(8); } else { WAITVM(0); }
    __builtin_amdgcn_s_barrier();
    if (t + 2 < TILES) { SUNIT(1, t + 2, 0, 0); SUNIT(1, t + 2, 0, 1); }
    WAITLGKM(0); SCHEDB();
    MFMA16(af, bfr, 4);
    LDA4(af, bufo, 8192, 0);
    LDB4(bfr, bufo, 8192);
    SCHEDB();

    // ---- p2: MFMA(ks1,mlo); tail: af <- ks1 mhi ----
    __builtin_amdgcn_s_barrier();
    if (t + 2 < TILES) { SUNIT(0, t + 2, 0, 0); SUNIT(0, t + 2, 0, 1); }
    WAITLGKM(0); SCHEDB();
    MFMA16(af, bfr, 0);
    LDA4(af, bufo, 8192, 2048);
    SCHEDB();

    // ---- p3: MFMA(ks1,mhi); tail: af,bfr <- next tile ks0 ----
    if (t < TILES - 2) { WAITVM(8); }
    else if (t == TILES - 2) { WAITVM(4); }   // stages skipped -> tighter
    __builtin_amdgcn_s_barrier();
    if (t + 2 < TILES) { SUNIT(1, t + 2, 1, 0); SUNIT(1, t + 2, 1, 1); }
    WAITLGKM(0); SCHEDB();
    MFMA16(af, bfr, 4);
    if (t + 1 < TILES) {
      LDA4(af, nbufo, 0, 0);
      LDB4(bfr, nbufo, 0);
      SCHEDB();
    }
  }
#undef LDA4
#undef LDB4
#undef MFMA16
#undef SUNIT

  // ================= epilogue: transpose + chunk scan =================
  __syncthreads();   // drains lgkm/vm; LDS reusable as sT[256][256] bf16

  // acc -> sT with bias; col swizzle col' = col ^ (q<<4) -> conflict-free
#pragma unroll
  for (int n = 0; n < 4; ++n) {
    const float bz = bias[bN + wc * 64 + n * 16 + lm];
#pragma unroll
    for (int M = 0; M < 8; ++M)
#pragma unroll
      for (int rr = 0; rr < 4; ++rr) {
        const int row = wr * 128 + M * 16 + q * 4 + rr;
        const int col = wc * 64 + ((n ^ q) * 16) + lm;   // swizzled store
        smem[row * 256 + col] = f2bf(acc[M][n][rr] + bz);
      }
  }
  __syncthreads();

  // lane scans a column over two 64-row chunks (zero init), in-place s store
  {
    const int col  = tid & 255;
    const int ch0  = (tid >> 8) * 2;
    const int gcol = bN + col;
    const float om  = TWO_PI_F * freq[gcol];
    const float osq = om * om;
    const float dp  = damp[gcol];
#pragma unroll
    for (int cc = 0; cc < 2; ++cc) {
      const int ch = ch0 + cc;
      float s = 0.f, v = 0.f;
#pragma unroll 8
      for (int i = 0; i < CL; ++i) {
        const int row = ch * 64 + i;
        const int idx = row * 256 + (col ^ (((i >> 2) & 3) << 4));
        float f = bf2f(smem[idx]);
        v += (-osq * s - dp * v + f) * DT;
        s += v * DT;
        smem[idx] = f2bf(s);
      }
      const int chunk = tm * 4 + ch;
      chunkS[chunk * NDIM + gcol] = s;
      chunkV[chunk * NDIM + gcol] = v;
    }
  }
  __syncthreads();

  // coalesced writeback of the 256x256 bf16 zpart tile (un-swizzling groups)
#pragma unroll
  for (int k = 0; k < 16; ++k) {
    const int slot = tid + 512 * k;
    const int row  = slot >> 5;
    const int grp  = slot & 31;
    const int sgrp = grp ^ (((row >> 2) & 3) << 1);
    *(uint4*)&zpart[(size_t)(bM + row) * NDIM + bN + grp * 8] =
        *(const uint4*)&smem[row * 256 + sgrp * 8];
  }
}

// ---- pass2 IN-PLACE: chunk partials -> carries (same array, 2 MB, ~2 us) ---
__global__ void scan_pass2_inplace(float* __restrict__ chunkS,
                                   float* __restrict__ chunkV,
                                   const float* __restrict__ freq,
                                   const float* __restrict__ damp) {
  int n = blockIdx.x * blockDim.x + threadIdx.x;     // 0..NDIM-1
  float om = TWO_PI_F * freq[n];
  float osq = om * om;
  float dp = damp[n];
  float a00 = 1.f - osq * DT * DT, a01 = DT * (1.f - dp * DT);
  float a10 = -osq * DT,           a11 = 1.f - dp * DT;
#pragma unroll
  for (int i = 0; i < 6; i++) {                      // M^64 by squaring
    float b00 = a00 * a00 + a01 * a10;
    float b01 = a00 * a01 + a01 * a11;
    float b10 = a10 * a00 + a11 * a10;
    float b11 = a10 * a01 + a11 * a11;
    a00 = b00; a01 = b01; a10 = b10; a11 = b11;
  }
  float cs = 0.f, cv = 0.f;
#pragma unroll 8
  for (int c = 0; c < CH; c++) {
    float ls = chunkS[c * NDIM + n];                 // read before overwrite
    float lv = chunkV[c * NDIM + n];
    chunkS[c * NDIM + n] = cs;
    chunkV[c * NDIM + n] = cv;
    float ns = a00 * cs + a01 * cv + ls;
    float nv = a10 * cs + a11 * cv + lv;
    cs = ns; cv = nv;
  }
}

// ---- kernel 3: carry load + homogeneous replay + osc/clip, fp32 out ----
__global__ void scan_out_carry4(const unsigned short* __restrict__ zpart,
                                const float* __restrict__ amp,
                                const float* __restrict__ freq,
                                const float* __restrict__ phase,
                                const float* __restrict__ damp,
                                const float* __restrict__ carryS,
                                const float* __restrict__ carryV,
                                float* __restrict__ out) {
  int gid = blockIdx.x * blockDim.x + threadIdx.x;   // 0 .. CH*4*NDIM/4
  int n4 = gid & (NDIM / 4 - 1);
  int cq = gid >> 10;            // chunk*4 + quarter
  int c  = cq >> 2;
  int qq = cq & 3;
  int n  = n4 * 4;

  float4 fr = *(const float4*)&freq[n];
  float4 dv = *(const float4*)&damp[n];
  float4 am = *(const float4*)&amp[n];
  float4 ph = *(const float4*)&phase[n];
  float omv[4] = {TWO_PI_F * fr.x, TWO_PI_F * fr.y, TWO_PI_F * fr.z, TWO_PI_F * fr.w};
  float dpv[4] = {dv.x, dv.y, dv.z, dv.w};
  float amv[4] = {am.x, am.y, am.z, am.w};
  float phv[4] = {ph.x, ph.y, ph.z, ph.w};
  float m00[4], m01[4], m10[4], m11[4], osc[4];
#pragma unroll
  for (int j = 0; j < 4; j++) {
    float osq = omv[j] * omv[j];
    m00[j] = 1.f - osq * DT * DT;  m01[j] = DT * (1.f - dpv[j] * DT);
    m10[j] = -osq * DT;            m11[j] = 1.f - dpv[j] * DT;
    osc[j] = amv[j] * sinf(omv[j] * DT + phv[j]);    // t = DT
  }

  // P = M^16 by squaring; J = P^qq; h = J * carry
  float4 csv = *(const float4*)&carryS[c * NDIM + n];
  float4 cvv = *(const float4*)&carryV[c * NDIM + n];
  float cs[4] = {csv.x, csv.y, csv.z, csv.w};
  float cv[4] = {cvv.x, cvv.y, cvv.z, cvv.w};
  float hs[4], hv[4];
#pragma unroll
  for (int j = 0; j < 4; j++) {
    float p00 = m00[j], p01 = m01[j], p10 = m10[j], p11 = m11[j];
#pragma unroll
    for (int k = 0; k < 4; k++) {                    // M^16
      float b00 = p00 * p00 + p01 * p10;
      float b01 = p00 * p01 + p01 * p11;
      float b10 = p10 * p00 + p11 * p10;
      float b11 = p10 * p01 + p11 * p11;
      p00 = b00; p01 = b01; p10 = b10; p11 = b11;
    }
    float j00 = 1.f, j01 = 0.f, j10 = 0.f, j11 = 1.f;
    for (int k = 0; k < qq; k++) {                   // wave-uniform qq
      float b00 = j00 * p00 + j01 * p10;
      float b01 = j00 * p01 + j01 * p11;
      float b10 = j10 * p00 + j11 * p10;
      float b11 = j10 * p01 + j11 * p11;
      j00 = b00; j01 = b01; j10 = b10; j11 = b11;
    }
    hs[j] = j00 * cs[j] + j01 * cv[j];
    hv[j] = j10 * cs[j] + j11 * cv[j];
  }

  const size_t r0 = (size_t)c * CL + qq * 16;
  const unsigned short* zp = zpart + r0 * NDIM + n;
  float* op = out + r0 * NDIM + n;
#pragma unroll 4
  for (int i = 0; i < 16; ++i) {
    ushort4 zv = *(const ushort4*)&zp[(size_t)i * NDIM];
    float z[4] = {bf2f(zv.x), bf2f(zv.y), bf2f(zv.z), bf2f(zv.w)};
    float o[4];
#pragma unroll
    for (int j = 0; j < 4; j++) {
      float t = m00[j] * hs[j] + m01[j] * hv[j];     // h = M h
      float u = m10[j] * hs[j] + m11[j] * hv[j];
      hs[j] = t; hv[j] = u;
      o[j] = fminf(1.f, fmaxf(-1.f, hs[j] + z[j] + osc[j]));
    }
    *(float4*)&op[(size_t)i * NDIM] = (float4){o[0], o[1], o[2], o[3]};
  }
}

// ============ FALLBACK PATH: exact round-7 pipeline (64 MiB ws) ============
__global__ __launch_bounds__(256, 2) void gemm_bt_kernel(
    const unsigned short* __restrict__ A,
    const unsigned short* __restrict__ Bm,
    const float* __restrict__ bias,
    unsigned short* __restrict__ C) {
  __shared__ __align__(16) unsigned short sA[128 * 32];
  __shared__ __align__(16) unsigned short sB[128 * 32];

  const int tid  = threadIdx.x;
  const int lane = tid & 63;
  const int wave = tid >> 6;
  const int wr = wave >> 1;
  const int wc = wave & 1;
  const int q  = lane >> 4;
  const int lm = lane & 15;

  const int bM = blockIdx.x * 128;
  const int bN = blockIdx.y * 128;

  f32x4 acc[4][4];
#pragma unroll
  for (int i = 0; i < 4; i++)
#pragma unroll
    for (int j = 0; j < 4; j++) acc[i][j] = (f32x4){0.f, 0.f, 0.f, 0.f};

  const int idx0 = tid;
  const int idx1 = tid + 256;
  const int r0 = idx0 >> 2, g0 = idx0 & 3;
  const int r1 = idx1 >> 2, g1 = idx1 & 3;
  const int dst0 = r0 * 32 + ((g0 ^ ((r0 >> 1) & 3)) * 8);
  const int dst1 = r1 * 32 + ((g1 ^ ((r1 >> 1) & 3)) * 8);
  const unsigned short* gA0 = A  + (size_t)(bM + r0) * KDIM + g0 * 8;
  const unsigned short* gA1 = A  + (size_t)(bM + r1) * KDIM + g1 * 8;
  const unsigned short* gB0 = Bm + (size_t)(bN + r0) * KDIM + g0 * 8;
  const unsigned short* gB1 = Bm + (size_t)(bN + r1) * KDIM + g1 * 8;
  const int rq = (q ^ ((lm >> 1) & 3)) * 8;

  for (int k0 = 0; k0 < KDIM; k0 += 32) {
    uint4 av0 = *(const uint4*)(gA0 + k0);
    uint4 av1 = *(const uint4*)(gA1 + k0);
    uint4 bv0 = *(const uint4*)(gB0 + k0);
    uint4 bv1 = *(const uint4*)(gB1 + k0);
    __syncthreads();
    *(uint4*)&sA[dst0] = av0;
    *(uint4*)&sA[dst1] = av1;
    *(uint4*)&sB[dst0] = bv0;
    *(uint4*)&sB[dst1] = bv1;
    __syncthreads();

    bf16x8 af[4], bfr[4];
#pragma unroll
    for (int mt = 0; mt < 4; mt++)
      af[mt]  = *(const bf16x8*)&sA[(wr * 64 + mt * 16 + lm) * 32 + rq];
#pragma unroll
    for (int nt = 0; nt < 4; nt++)
      bfr[nt] = *(const bf16x8*)&sB[(wc * 64 + nt * 16 + lm) * 32 + rq];

#pragma unroll
    for (int mt = 0; mt < 4; mt++)
#pragma unroll
      for (int nt = 0; nt < 4; nt++)
        acc[mt][nt] = __builtin_amdgcn_mfma_f32_16x16x32_bf16(
            af[mt], bfr[nt], acc[mt][nt], 0, 0, 0);
  }

#pragma unroll
  for (int nt = 0; nt < 4; nt++) {
    const int col = bN + wc * 64 + nt * 16 + lm;
    const float bz = bias[col];
#pragma unroll
    for (int mt = 0; mt < 4; mt++) {
      const int row0 = bM + wr * 64 + mt * 16 + q * 4;
#pragma unroll
      for (int r = 0; r < 4; r++)
        C[(size_t)(row0 + r) * NDIM + col] = f2bf(acc[mt][nt][r] + bz);
    }
  }
}

__global__ void scan_pass1(const unsigned short* __restrict__ force,
                           const float* __restrict__ freq,
                           const float* __restrict__ damp,
                           float* __restrict__ chunkS,
                           float* __restrict__ chunkV) {
  int gid = blockIdx.x * blockDim.x + threadIdx.x;
  int n4 = gid & (NDIM / 4 - 1);
  int c  = gid >> 10;
  int n  = n4 * 4;
  float4 fr = *(const float4*)&freq[n];
  float4 dv = *(const float4*)&damp[n];
  float osq[4] = {TWO_PI_F * fr.x, TWO_PI_F * fr.y, TWO_PI_F * fr.z, TWO_PI_F * fr.w};
  float dp[4]  = {dv.x, dv.y, dv.z, dv.w};
  float s[4] = {0.f, 0.f, 0.f, 0.f}, v[4] = {0.f, 0.f, 0.f, 0.f};
#pragma unroll
  for (int j = 0; j < 4; j++) osq[j] *= osq[j];
  const unsigned short* fp = force + (size_t)c * CL * NDIM + n;
#pragma unroll 4
  for (int i = 0; i < CL; i++) {
    ushort4 fv = *(const ushort4*)&fp[(size_t)i * NDIM];
    float f[4] = {bf2f(fv.x), bf2f(fv.y), bf2f(fv.z), bf2f(fv.w)};
#pragma unroll
    for (int j = 0; j < 4; j++) {
      float a = -osq[j] * s[j] - dp[j] * v[j] + f[j];
      v[j] += a * DT;
      s[j] += v[j] * DT;
    }
  }
  *(float4*)&chunkS[c * NDIM + n] = (float4){s[0], s[1], s[2], s[3]};
  *(float4*)&chunkV[c * NDIM + n] = (float4){v[0], v[1], v[2], v[3]};
}

__global__ void scan_pass2(const float* __restrict__ chunkS,
                           const float* __restrict__ chunkV,
                           const float* __restrict__ freq,
                           const float* __restrict__ damp,
                           float* __restrict__ carryS,
                           float* __restrict__ carryV) {
  int n = blockIdx.x * blockDim.x + threadIdx.x;
  float om = TWO_PI_F * freq[n];
  float osq = om * om;
  float dp = damp[n];
  float a00 = 1.f - osq * DT * DT, a01 = DT * (1.f - dp * DT);
  float a10 = -osq * DT,           a11 = 1.f - dp * DT;
#pragma unroll
  for (int i = 0; i < 6; i++) {
    float b00 = a00 * a00 + a01 * a10;
    float b01 = a00 * a01 + a01 * a11;
    float b10 = a10 * a00 + a11 * a10;
    float b11 = a10 * a01 + a11 * a11;
    a00 = b00; a01 = b01; a10 = b10; a11 = b11;
  }
  float cs = 0.f, cv = 0.f;
#pragma unroll 8
  for (int c = 0; c < CH; c++) {
    carryS[c * NDIM + n] = cs;
    carryV[c * NDIM + n] = cv;
    float ls = chunkS[c * NDIM + n];
    float lv = chunkV[c * NDIM + n];
    float ns = a00 * cs + a01 * cv + ls;
    float nv = a10 * cs + a11 * cv + lv;
    cs = ns; cv = nv;
  }
}

__global__ void scan_pass3(const unsigned short* __restrict__ force,
                           const float* __restrict__ amp,
                           const float* __restrict__ freq,
                           const float* __restrict__ phase,
                           const float* __restrict__ damp,
                           const float* __restrict__ carryS,
                           const float* __restrict__ carryV,
                           float* __restrict__ out) {
  int gid = blockIdx.x * blockDim.x + threadIdx.x;
  int n4 = gid & (NDIM / 4 - 1);
  int c  = gid >> 10;
  int n  = n4 * 4;
  float4 fr = *(const float4*)&freq[n];
  float4 dv = *(const float4*)&damp[n];
  float4 am = *(const float4*)&amp[n];
  float4 ph = *(const float4*)&phase[n];
  float om[4] = {TWO_PI_F * fr.x, TWO_PI_F * fr.y, TWO_PI_F * fr.z, TWO_PI_F * fr.w};
  float dp[4] = {dv.x, dv.y, dv.z, dv.w};
  float osq[4], osc[4], s[4], v[4];
  float amv[4] = {am.x, am.y, am.z, am.w};
  float phv[4] = {ph.x, ph.y, ph.z, ph.w};
#pragma unroll
  for (int j = 0; j < 4; j++) {
    osq[j] = om[j] * om[j];
    osc[j] = amv[j] * sinf(om[j] * DT + phv[j]);
  }
  float4 csv = *(const float4*)&carryS[c * NDIM + n];
  float4 cvv = *(const float4*)&carryV[c * NDIM + n];
  s[0] = csv.x; s[1] = csv.y; s[2] = csv.z; s[3] = csv.w;
  v[0] = cvv.x; v[1] = cvv.y; v[2] = cvv.z; v[3] = cvv.w;
  const unsigned short* fp = force + (size_t)c * CL * NDIM + n;
  float* op = out + (size_t)c * CL * NDIM + n;
#pragma unroll 4
  for (int i = 0; i < CL; i++) {
    ushort4 fv = *(const ushort4*)&fp[(size_t)i * NDIM];
    float f[4] = {bf2f(fv.x), bf2f(fv.y), bf2f(fv.z), bf2f(fv.w)};
    float o[4];
#pragma unroll
    for (int j = 0; j < 4; j++) {
      float a = -osq[j] * s[j] - dp[j] * v[j] + f[j];
      v[j] += a * DT;
      s[j] += v[j] * DT;
      o[j] = fminf(1.f, fmaxf(-1.f, s[j] + osc[j]));
    }
    *(float4*)&op[(size_t)i * NDIM] = (float4){o[0], o[1], o[2], o[3]};
  }
}

// ---------------- launch ----------------
extern "C" void kernel_launch(void* const* d_in, const int* in_sizes, int n_in,
                              void* d_out, int out_size, void* d_ws, size_t ws_size,
                              hipStream_t stream) {
  const float* x     = (const float*)d_in[0];
  const float* W     = (const float*)d_in[1];
  const float* bias  = (const float*)d_in[2];
  const float* amp   = (const float*)d_in[3];
  const float* freq  = (const float*)d_in[4];
  const float* phase = (const float*)d_in[5];
  const float* damp  = (const float*)d_in[6];

  const size_t MiB = 1024 * 1024;
  const int n4each = MDIM * KDIM / 4;

  if (ws_size >= 66 * MiB) {
    // fused path (66 MiB):
    // xbf[0,16Mi) wbf[16,32Mi) zpart[32,64Mi) chunkS/V[64,66Mi)
    unsigned short* xbf   = (unsigned short*)d_ws;
    unsigned short* wbf   = xbf + (size_t)MDIM * KDIM;
    unsigned short* zpart = wbf + (size_t)NDIM * KDIM;
    float* chunkS = (float*)((char*)d_ws + 64 * MiB);
    float* chunkV = chunkS + CH * NDIM;

    static bool attr_done = false;
    if (!attr_done) {
      (void)hipFuncSetAttribute((const void*)gemm_scan256_kernel,
                                hipFuncAttributeMaxDynamicSharedMemorySize,
                                131072);
      attr_done = true;
    }

    cast2_bf16_kernel<<<(2 * n4each + 255) / 256, 256, 0, stream>>>(
        x, xbf, W, wbf, n4each);
    gemm_scan256_kernel<<<dim3(256), dim3(512), 131072, stream>>>(
        xbf, wbf, bias, freq, damp, zpart, chunkS, chunkV);
    scan_pass2_inplace<<<NDIM / 256, 256, 0, stream>>>(chunkS, chunkV,
                                                       freq, damp);
    // chunkS/V now hold carries (in-place)
    scan_out_carry4<<<CH * 4 * NDIM / 4 / 256, 256, 0, stream>>>(
        zpart, amp, freq, phase, damp, chunkS, chunkV, (float*)d_out);
  } else {
    // fallback: exact round-7 pipeline (proven, 64 MiB)
    dim3 gg(MDIM / 128, NDIM / 128);
    unsigned short* xbf   = (unsigned short*)d_ws;
    unsigned short* wbf   = xbf + (size_t)MDIM * KDIM;
    unsigned short* force = wbf + (size_t)NDIM * KDIM;
    float* chunkS = (float*)d_ws;            // aliases xbf: dead after GEMM
    float* chunkV = chunkS + CH * NDIM;
    float* carryS = chunkV + CH * NDIM;
    float* carryV = carryS + CH * NDIM;

    cast2_bf16_kernel<<<(2 * n4each + 255) / 256, 256, 0, stream>>>(
        x, xbf, W, wbf, n4each);
    gemm_bt_kernel<<<gg, 256, 0, stream>>>(xbf, wbf, bias, force);
    scan_pass1<<<CH * NDIM / 4 / 256, 256, 0, stream>>>(force, freq, damp,
                                                        chunkS, chunkV);
    scan_pass2<<<NDIM / 256, 256, 0, stream>>>(chunkS, chunkV, freq, damp,
                                               carryS, carryV);
    scan_pass3<<<CH * NDIM / 4 / 256, 256, 0, stream>>>(
        force, amp, freq, phase, damp, carryS, carryV, (float*)d_out);
  }
}